// Round 8
// baseline (505.158 us; speedup 1.0000x reference)
//
#include <hip/hip_runtime.h>

#define IMG_H 512
#define IMG_W 512
#define NCH 3
#define NB 32
#define NIMG (NB * NCH)      // 96
#define SEG 64               // output rows per wave
#define NSEG (IMG_H / SEG)   // 8
#define NCW 9                // col-waves per image; each outputs 57 cols (lanes 3..59)
#define WPB 4                // waves per 256-thread block

// pull value of v from lane (addr>>2)&63
__device__ __forceinline__ float bperm(int addr, float v) {
    return __int_as_float(__builtin_amdgcn_ds_bpermute(addr, __float_as_int(v)));
}

// Column-walk SSIM: lane owns ONE column; wave covers 64 cols (57 useful) and
// walks 70 input rows of a 64-output-row segment. Vertical 7-window kept as 5
// running sums slid with a 7-deep REGISTER ring of raw pixels (no reloads —
// every input byte fetched exactly once). Loads flow through a 7-iteration
// prefetch pipeline (~1400 cyc cover). Horizontal 7-window via ds_bpermute
// across lanes. No LDS tiles, no barriers.
__global__ __launch_bounds__(256) void ssim_kernel(const float* __restrict__ x,
                                                   const float* __restrict__ y,
                                                   float* __restrict__ out)
{
    const int tid  = threadIdx.x;
    const int lane = tid & 63;
    const int wid  = blockIdx.x * WPB + (tid >> 6);
    const int img  = wid / (NSEG * NCW);
    const int rem  = wid % (NSEG * NCW);
    const int seg  = rem / NCW;
    const int cw   = rem % NCW;          // cw innermost: block's 4 waves = adjacent col-strips
    const int r0   = seg * SEG;
    const int c0   = cw * 57;
    const int col  = c0 - 3 + lane;      // -3..516
    const bool inb = (col >= 0) && (col < IMG_W);
    const int  ccl = col < 0 ? 0 : (col >= IMG_W ? IMG_W - 1 : col);
    const float vmask = (lane >= 3 && lane <= 59 && col < IMG_W) ? 1.0f : 0.0f;
    const int obase = img * (IMG_H * IMG_W) + ccl;   // max ~25.2M, int-safe

    // bpermute byte-address vectors (computed once; wrap garbage only hits masked lanes)
    const int am3 = (lane - 3) << 2, am2 = (lane - 2) << 2, am1 = (lane - 1) << 2;
    const int ap1 = (lane + 1) << 2, ap2 = (lane + 2) << 2, ap3 = (lane + 3) << 2;

    float rxr[7], ryr[7];   // ring: raw rows of the vertical window
    float pxr[7], pyr[7];   // prefetch pipeline, 7 rows ahead

    // ring prefill: slot k holds row r0+k-4. Slot 0 is the row subtracted at
    // u=0 (row r0-4): force 0 — it was never added to the running sums.
    rxr[0] = 0.f; ryr[0] = 0.f;
    #pragma unroll
    for (int k = 1; k < 7; ++k) {
        const int row = r0 + k - 4;          // r0-3 .. r0+2 (< IMG_H always)
        float xv = 0.f, yv = 0.f;
        if (row >= 0) {                      // wave-uniform
            xv = x[obase + row * IMG_W]; xv = inb ? xv : 0.f;
            yv = y[obase + row * IMG_W]; yv = inb ? yv : 0.f;
        }
        rxr[k] = xv; ryr[k] = yv;
    }
    // pf prefill: slot j holds row r0+3+j (<= 457 < IMG_H always)
    #pragma unroll
    for (int j = 0; j < 7; ++j) {
        const int row = r0 + 3 + j;
        float xv = x[obase + row * IMG_W]; xv = inb ? xv : 0.f;
        float yv = y[obase + row * IMG_W]; yv = inb ? yv : 0.f;
        pxr[j] = xv; pyr[j] = yv;
    }

    // vertical running sums over rows r0-3 .. r0+2
    float vx = 0.f, vy = 0.f, vxx = 0.f, vyy = 0.f, vxy = 0.f;
    #pragma unroll
    for (int k = 1; k < 7; ++k) {
        vx += rxr[k]; vy += ryr[k];
        vxx = fmaf(rxr[k], rxr[k], vxx);
        vyy = fmaf(ryr[k], ryr[k], vyy);
        vxy = fmaf(rxr[k], ryr[k], vxy);
    }

    const float inv49 = 1.0f / 49.0f, C1v = 1e-4f, C2v = 9e-4f;
    float acc = 0.f;

    // 64 output rows: 9 unrolled blocks of 7 (u=0..62) + tail (u=63, slot 0).
    // Slot index u%7 == j is compile-time static inside the unroll.
    for (int t = 0; t < 9; ++t) {
        #pragma unroll
        for (int j = 0; j < 7; ++j) {
            const int u = t * 7 + j;
            const float xn = pxr[j], yn = pyr[j];   // row r0+u+3 (prefetched)
            const float xo = rxr[j], yo = ryr[j];   // row r0+u-4 (leaving)
            // refill pf slot with row r0+u+10 (consumed at u+7; skip if never used)
            if (u < 57) {                            // wave-uniform scalar branch
                const int rowf = r0 + u + 10;
                float xf = 0.f, yf = 0.f;
                if (rowf < IMG_H) {
                    xf = x[obase + rowf * IMG_W]; xf = inb ? xf : 0.f;
                    yf = y[obase + rowf * IMG_W]; yf = inb ? yf : 0.f;
                }
                pxr[j] = xf; pyr[j] = yf;
            }
            // vertical window slide: rows [r0+u-3 .. r0+u+3]
            const float dx = xn - xo, sx = xn + xo;
            const float dy = yn - yo, sy = yn + yo;
            vx += dx; vy += dy;
            vxx = fmaf(dx, sx, vxx);
            vyy = fmaf(dy, sy, vyy);
            vxy = fmaf(xn, yn, vxy - xo * yo);
            rxr[j] = xn; ryr[j] = yn;
            // horizontal 7-window across lanes for the 5 running sums
            const float Sx  = vx  + bperm(am3, vx)  + bperm(am2, vx)  + bperm(am1, vx)
                                  + bperm(ap1, vx)  + bperm(ap2, vx)  + bperm(ap3, vx);
            const float Sy  = vy  + bperm(am3, vy)  + bperm(am2, vy)  + bperm(am1, vy)
                                  + bperm(ap1, vy)  + bperm(ap2, vy)  + bperm(ap3, vy);
            const float Sxx = vxx + bperm(am3, vxx) + bperm(am2, vxx) + bperm(am1, vxx)
                                  + bperm(ap1, vxx) + bperm(ap2, vxx) + bperm(ap3, vxx);
            const float Syy = vyy + bperm(am3, vyy) + bperm(am2, vyy) + bperm(am1, vyy)
                                  + bperm(ap1, vyy) + bperm(ap2, vyy) + bperm(ap3, vyy);
            const float Sxy = vxy + bperm(am3, vxy) + bperm(am2, vxy) + bperm(am1, vxy)
                                  + bperm(ap1, vxy) + bperm(ap2, vxy) + bperm(ap3, vxy);
            // SSIM
            const float mx = Sx * inv49, my = Sy * inv49;
            const float sxx = fmaf(-mx, mx, Sxx * inv49);
            const float syy = fmaf(-my, my, Syy * inv49);
            const float sxy = fmaf(-mx, my, Sxy * inv49);
            const float num = fmaf(2.f * mx, my, C1v) * fmaf(2.f, sxy, C2v);
            const float den = fmaf(mx, mx, fmaf(my, my, C1v)) * (sxx + syy + C2v);
            acc = fmaf(num * __builtin_amdgcn_rcpf(den + 1e-12f), vmask, acc);
        }
    }
    {   // tail: u = 63, slot 0, no refill
        const float xn = pxr[0], yn = pyr[0];
        const float xo = rxr[0], yo = ryr[0];
        const float dx = xn - xo, sx = xn + xo;
        const float dy = yn - yo, sy = yn + yo;
        vx += dx; vy += dy;
        vxx = fmaf(dx, sx, vxx);
        vyy = fmaf(dy, sy, vyy);
        vxy = fmaf(xn, yn, vxy - xo * yo);
        const float Sx  = vx  + bperm(am3, vx)  + bperm(am2, vx)  + bperm(am1, vx)
                              + bperm(ap1, vx)  + bperm(ap2, vx)  + bperm(ap3, vx);
        const float Sy  = vy  + bperm(am3, vy)  + bperm(am2, vy)  + bperm(am1, vy)
                              + bperm(ap1, vy)  + bperm(ap2, vy)  + bperm(ap3, vy);
        const float Sxx = vxx + bperm(am3, vxx) + bperm(am2, vxx) + bperm(am1, vxx)
                              + bperm(ap1, vxx) + bperm(ap2, vxx) + bperm(ap3, vxx);
        const float Syy = vyy + bperm(am3, vyy) + bperm(am2, vyy) + bperm(am1, vyy)
                              + bperm(ap1, vyy) + bperm(ap2, vyy) + bperm(ap3, vyy);
        const float Sxy = vxy + bperm(am3, vxy) + bperm(am2, vxy) + bperm(am1, vxy)
                              + bperm(ap1, vxy) + bperm(ap2, vxy) + bperm(ap3, vxy);
        const float mx = Sx * inv49, my = Sy * inv49;
        const float sxx = fmaf(-mx, mx, Sxx * inv49);
        const float syy = fmaf(-my, my, Syy * inv49);
        const float sxy = fmaf(-mx, my, Sxy * inv49);
        const float num = fmaf(2.f * mx, my, C1v) * fmaf(2.f, sxy, C2v);
        const float den = fmaf(mx, mx, fmaf(my, my, C1v)) * (sxx + syy + C2v);
        acc = fmaf(num * __builtin_amdgcn_rcpf(den + 1e-12f), vmask, acc);
    }

    // wave reduction + one atomic per wave
    #pragma unroll
    for (int off = 32; off; off >>= 1) acc += __shfl_down(acc, off, 64);
    if (lane == 0)
        atomicAdd(&out[img / NCH], acc * (1.0f / ((float)NCH * IMG_H * IMG_W)));
}

extern "C" void kernel_launch(void* const* d_in, const int* in_sizes, int n_in,
                              void* d_out, int out_size, void* d_ws, size_t ws_size,
                              hipStream_t stream) {
    const float* x = (const float*)d_in[0];
    const float* y = (const float*)d_in[1];
    float* out = (float*)d_out;
    hipMemsetAsync(out, 0, sizeof(float) * NB, stream);
    const int nwaves = NIMG * NSEG * NCW;            // 6912
    ssim_kernel<<<nwaves / WPB, 256, 0, stream>>>(x, y, out);
}

// Round 9
// 256.236 us; speedup vs baseline: 1.9715x; 1.9715x over previous
//
#include <hip/hip_runtime.h>

#define IMG_H 512
#define IMG_W 512
#define NCH 3
#define NB 32
#define RSTRIP 16
#define NSTRIP (IMG_H / RSTRIP)   // 32 strips per channel-image

// One wave owns a 512-wide strip of RSTRIP output rows; lane owns 8 cols.
// Vertical 7-tap window = 5 running column-sums, slid by adding row r+4 and
// re-loading/subtracting row r-3. Horizontal 7-tap via lane-neighbor shfl of
// the vertical sums. Software-pipelined: loads for iteration u+1 are issued
// into a second register buffer BEFORE computing iteration u, so shuffle+SSIM
// work (~350cyc) covers load latency. Needs ~160 VGPR: NO min-wave
// launch_bounds (R4: capping at 64 VGPR caused 1.4GB scratch spill traffic).
__global__ __launch_bounds__(256) void ssim_kernel(const float* __restrict__ x,
                                                   const float* __restrict__ y,
                                                   float* __restrict__ out)
{
    const int tid  = threadIdx.x;
    const int lane = tid & 63;
    const int wid  = (blockIdx.x << 2) + (tid >> 6);
    const int b     = wid / (NCH * NSTRIP);
    const int rem   = wid % (NCH * NSTRIP);
    const int ch    = rem / NSTRIP;
    const int strip = rem % NSTRIP;
    const int r0    = strip * RSTRIP;

    const int ibase = (b * NCH + ch) * (IMG_H * IMG_W) + lane * 8;  // int-safe
    const float* __restrict__ xp = x + ibase;
    const float* __restrict__ yp = y + ibase;

    float vsx[8], vsy[8], vsxx[8], vsyy[8], vsxy[8];
    #pragma unroll
    for (int i = 0; i < 8; ++i) { vsx[i]=vsy[i]=vsxx[i]=vsyy[i]=vsxy[i]=0.f; }

    // ---- prologue: accumulate rows r0-3 .. r0+3 (zero-padded outside) ----
    #pragma unroll
    for (int j = -3; j <= 3; ++j) {
        const int rr = r0 + j;
        if (rr >= 0 && rr < IMG_H) {
            const int ro = rr * IMG_W;
            float xn[8], yn[8];
            *(float4*)&xn[0] = *(const float4*)(xp + ro);
            *(float4*)&xn[4] = *(const float4*)(xp + ro + 4);
            *(float4*)&yn[0] = *(const float4*)(yp + ro);
            *(float4*)&yn[4] = *(const float4*)(yp + ro + 4);
            #pragma unroll
            for (int i = 0; i < 8; ++i) {
                vsx[i] += xn[i];
                vsy[i] += yn[i];
                vsxx[i] = fmaf(xn[i], xn[i], vsxx[i]);
                vsyy[i] = fmaf(yn[i], yn[i], vsyy[i]);
                vsxy[i] = fmaf(xn[i], yn[i], vsxy[i]);
            }
        }
    }

    const float C1v = 1e-4f;
    const float C2v = 9e-4f;
    const float inv49 = 1.0f / 49.0f;
    float acc = 0.f;

    float xnA[8], ynA[8], xoA[8], yoA[8];
    float xnB[8], ynB[8], xoB[8], yoB[8];

// issue the slide loads for iteration U into buffer (XN,YN,XO,YO)
#define LOADS(U, XN, YN, XO, YO)                                            \
    {                                                                       \
        _Pragma("unroll")                                                   \
        for (int i = 0; i < 8; ++i) { XN[i]=YN[i]=XO[i]=YO[i]=0.f; }        \
        if ((U) < RSTRIP - 1) {                                             \
            const int ra = r0 + (U) + 4, rs = r0 + (U) - 3;                 \
            if (ra < IMG_H) {                                               \
                const int ro = ra * IMG_W;                                  \
                *(float4*)&XN[0] = *(const float4*)(xp + ro);               \
                *(float4*)&XN[4] = *(const float4*)(xp + ro + 4);           \
                *(float4*)&YN[0] = *(const float4*)(yp + ro);               \
                *(float4*)&YN[4] = *(const float4*)(yp + ro + 4);           \
            }                                                               \
            if (rs >= 0) {                                                  \
                const int ro = rs * IMG_W;                                  \
                *(float4*)&XO[0] = *(const float4*)(xp + ro);               \
                *(float4*)&XO[4] = *(const float4*)(xp + ro + 4);           \
                *(float4*)&YO[0] = *(const float4*)(yp + ro);               \
                *(float4*)&YO[4] = *(const float4*)(yp + ro + 4);           \
            }                                                               \
        }                                                                   \
    }

// compute iteration U: shuffles + hsum + SSIM from current vsums, then slide
#define COMPUTE(U, XN, YN, XO, YO)                                          \
    {                                                                       \
        float hlx[3], hly[3], hlxx[3], hlyy[3], hlxy[3];                    \
        float hrx[3], hry[3], hrxx[3], hryy[3], hrxy[3];                    \
        _Pragma("unroll")                                                   \
        for (int k = 0; k < 3; ++k) {                                       \
            float t;                                                        \
            t = __shfl_up(vsx[5+k], 1, 64);  hlx[k]  = (lane == 0)  ? 0.f : t; \
            t = __shfl_up(vsy[5+k], 1, 64);  hly[k]  = (lane == 0)  ? 0.f : t; \
            t = __shfl_up(vsxx[5+k], 1, 64); hlxx[k] = (lane == 0)  ? 0.f : t; \
            t = __shfl_up(vsyy[5+k], 1, 64); hlyy[k] = (lane == 0)  ? 0.f : t; \
            t = __shfl_up(vsxy[5+k], 1, 64); hlxy[k] = (lane == 0)  ? 0.f : t; \
            t = __shfl_down(vsx[k], 1, 64);  hrx[k]  = (lane == 63) ? 0.f : t; \
            t = __shfl_down(vsy[k], 1, 64);  hry[k]  = (lane == 63) ? 0.f : t; \
            t = __shfl_down(vsxx[k], 1, 64); hrxx[k] = (lane == 63) ? 0.f : t; \
            t = __shfl_down(vsyy[k], 1, 64); hryy[k] = (lane == 63) ? 0.f : t; \
            t = __shfl_down(vsxy[k], 1, 64); hrxy[k] = (lane == 63) ? 0.f : t; \
        }                                                                   \
        float hx  = hlx[0]+hlx[1]+hlx[2]+vsx[0]+vsx[1]+vsx[2]+vsx[3];       \
        float hy  = hly[0]+hly[1]+hly[2]+vsy[0]+vsy[1]+vsy[2]+vsy[3];       \
        float hxx = hlxx[0]+hlxx[1]+hlxx[2]+vsxx[0]+vsxx[1]+vsxx[2]+vsxx[3];\
        float hyy = hlyy[0]+hlyy[1]+hlyy[2]+vsyy[0]+vsyy[1]+vsyy[2]+vsyy[3];\
        float hxy = hlxy[0]+hlxy[1]+hlxy[2]+vsxy[0]+vsxy[1]+vsxy[2]+vsxy[3];\
        _Pragma("unroll")                                                   \
        for (int i = 0; i < 8; ++i) {                                       \
            if (i > 0) {                                                    \
                const float ax  = (i+6 < 11) ? vsx[i+3]  : hrx[i-5];        \
                const float ay  = (i+6 < 11) ? vsy[i+3]  : hry[i-5];        \
                const float axx = (i+6 < 11) ? vsxx[i+3] : hrxx[i-5];       \
                const float ayy = (i+6 < 11) ? vsyy[i+3] : hryy[i-5];       \
                const float axy = (i+6 < 11) ? vsxy[i+3] : hrxy[i-5];       \
                const float sx_ = (i-1 < 3) ? hlx[i-1]  : vsx[i-4];         \
                const float sy_ = (i-1 < 3) ? hly[i-1]  : vsy[i-4];         \
                const float sxx_= (i-1 < 3) ? hlxx[i-1] : vsxx[i-4];        \
                const float syy_= (i-1 < 3) ? hlyy[i-1] : vsyy[i-4];        \
                const float sxy_= (i-1 < 3) ? hlxy[i-1] : vsxy[i-4];        \
                hx += ax - sx_;  hy += ay - sy_;                            \
                hxx += axx - sxx_; hyy += ayy - syy_; hxy += axy - sxy_;    \
            }                                                               \
            const float mx = hx * inv49, my = hy * inv49;                   \
            const float sxx = fmaf(-mx, mx, hxx * inv49);                   \
            const float syy = fmaf(-my, my, hyy * inv49);                   \
            const float sxy = fmaf(-mx, my, hxy * inv49);                   \
            const float num = fmaf(2.f * mx, my, C1v) * fmaf(2.f, sxy, C2v);\
            const float den = fmaf(mx, mx, fmaf(my, my, C1v)) * (sxx + syy + C2v); \
            acc += num * __builtin_amdgcn_rcpf(den + 1e-12f);               \
        }                                                                   \
        if ((U) < RSTRIP - 1) {                                             \
            _Pragma("unroll")                                               \
            for (int i = 0; i < 8; ++i) {                                   \
                const float dx = XN[i] - XO[i], sx = XN[i] + XO[i];         \
                const float dy = YN[i] - YO[i], sy = YN[i] + YO[i];         \
                vsx[i] += dx;                                               \
                vsy[i] += dy;                                               \
                vsxx[i] = fmaf(dx, sx, vsxx[i]);                            \
                vsyy[i] = fmaf(dy, sy, vsyy[i]);                            \
                vsxy[i] = fmaf(XN[i], YN[i], vsxy[i] - XO[i] * YO[i]);      \
            }                                                               \
        }                                                                   \
    }

    // software pipeline, distance 1: loads for u+1 in flight during compute u
    LOADS(0, xnA, ynA, xoA, yoA);
    for (int t = 0; t < RSTRIP / 2; ++t) {
        const int u = 2 * t;
        LOADS(u + 1, xnB, ynB, xoB, yoB);
        COMPUTE(u, xnA, ynA, xoA, yoA);
        LOADS(u + 2, xnA, ynA, xoA, yoA);
        COMPUTE(u + 1, xnB, ynB, xoB, yoB);
    }
#undef LOADS
#undef COMPUTE

    // wave reduction + one atomic per wave
    #pragma unroll
    for (int off = 32; off; off >>= 1) acc += __shfl_down(acc, off, 64);
    if (lane == 0)
        atomicAdd(&out[b], acc * (1.0f / ((float)NCH * IMG_H * IMG_W)));
}

extern "C" void kernel_launch(void* const* d_in, const int* in_sizes, int n_in,
                              void* d_out, int out_size, void* d_ws, size_t ws_size,
                              hipStream_t stream) {
    const float* x = (const float*)d_in[0];
    const float* y = (const float*)d_in[1];
    float* out = (float*)d_out;
    hipMemsetAsync(out, 0, sizeof(float) * NB, stream);
    const int nwaves = NB * NCH * NSTRIP;       // 3072
    ssim_kernel<<<nwaves / 4, 256, 0, stream>>>(x, y, out);
}